// Round 12
// baseline (37.606 us; speedup 1.0000x reference)
//
#include <hip/hip_runtime.h>

#define NB 512
#define NN 1000
#define ND 128
#define NS 8
#define THREADS 1024
#define NSTREAM 32
#define NWAVE 16

static constexpr float NORM_LOG2E = 0.12752455581290256f; // (1/sqrt(128)) * log2(e)

typedef float vf4 __attribute__((ext_vector_type(4)));

// 32-lane all-lanes sum: 4 DPP (VALU) + 1 ds_swizzle(xor16).
__device__ __forceinline__ float red32(float v) {
    int x;
    x = __float_as_int(v);
    v += __int_as_float(__builtin_amdgcn_update_dpp(0, x, 0xB1, 0xF, 0xF, true));  // quad_perm xor1
    x = __float_as_int(v);
    v += __int_as_float(__builtin_amdgcn_update_dpp(0, x, 0x4E, 0xF, 0xF, true));  // quad_perm xor2
    x = __float_as_int(v);
    v += __int_as_float(__builtin_amdgcn_update_dpp(0, x, 0x124, 0xF, 0xF, true)); // row_ror:4
    x = __float_as_int(v);
    v += __int_as_float(__builtin_amdgcn_update_dpp(0, x, 0x128, 0xF, 0xF, true)); // row_ror:8
    x = __float_as_int(v);
    v += __int_as_float(__builtin_amdgcn_ds_swizzle(x, 0x401F));                   // xor16
    return v;
}

__global__ __launch_bounds__(THREADS, 8)
void attn_edge_kernel(const float* __restrict__ node_emb,
                      const float* __restrict__ state,
                      const int* __restrict__ curr_id,
                      const int* __restrict__ next_id,
                      const int* __restrict__ mask,
                      const float* __restrict__ w_q,
                      const float* __restrict__ w_k,
                      const float* __restrict__ w_v,
                      const float* __restrict__ w_state,
                      const float* __restrict__ b_state,
                      const float* __restrict__ w_out,
                      const float* __restrict__ b_out,
                      float* __restrict__ out)
{
    const int b = blockIdx.x;
    const int tid = threadIdx.x;
    const int lane = tid & 63;
    const int wv = tid >> 6;          // wave 0..15
    const int half = lane >> 5;       // half-wave 0/1
    const int la = lane & 31;         // lane in half
    const int stream = wv * 2 + half; // 32 (wv,half) slots

    __shared__ __align__(16) float s_inq[3*ND];   // [curr | next | state_emb]
    __shared__ __align__(16) float s_q[ND];
    __shared__ __align__(16) float s_qk[ND];      // later reused for hn
    __shared__ __align__(16) float s_red[THREADS];
    __shared__ __align__(16) float s_acc[NSTREAM][ND];
    __shared__ __align__(16) float s_h[ND];
    __shared__ float s_l[NSTREAM];                // per-slot exp-sums
    __shared__ unsigned short s_idx[1024];        // compacted valid-node list
    __shared__ int s_cnt[NWAVE];

    const float* nb_row = node_emb + (size_t)b * NN * ND;
    const int* mrow = mask + (size_t)b * NN;

    // ---- compact valid nodes: wave w covers [w*64, w*64+64) ----
    {
        const int n = wv * 64 + lane;
        const int mv = (n < NN) ? mrow[n] : 0;
        const unsigned long long bal = __ballot(mv != 0);
        if (lane == 0) s_cnt[wv] = __popcll(bal);
        __syncthreads();
        int base = 0;
#pragma unroll
        for (int w = 0; w < NWAVE; ++w) base += (w < wv) ? s_cnt[w] : 0;
        if (mv) {
            const int pos = base + __popcll(bal & ((1ULL << lane) - 1ULL));
            s_idx[pos] = (unsigned short)n;
        }
    }

    // ---- input_q = [curr_emb, next_emb, state_emb] ----
    if (tid < ND) {
        const int cid = curr_id[b];
        const int nid = next_id[b];
        s_inq[tid]      = nb_row[(size_t)cid * ND + tid];
        s_inq[ND + tid] = nb_row[(size_t)nid * ND + tid];
        float se = b_state[tid];
#pragma unroll
        for (int s = 0; s < NS; ++s)
            se = fmaf(state[b*NS + s], w_state[tid*NS + s], se);
        s_inq[2*ND + tid] = se;
    }
    __syncthreads();

    int C = 0;  // total valid count (wave-uniform)
#pragma unroll
    for (int w = 0; w < NWAVE; ++w) C += s_cnt[w];

    const int d  = tid & (ND-1);
    const int ch = tid >> 7;          // chunk 0..7

    // ---- q[d] = sum_e inq[e] * w_q[e,d]  (384 rows over 8 chunks of 48) ----
    {
        float a = 0.f;
#pragma unroll 4
        for (int e = ch*48; e < ch*48 + 48; ++e)
            a = fmaf(s_inq[e], w_q[e*ND + d], a);
        s_red[tid] = a;
    }
    __syncthreads();
    if (tid < ND) {
        float a = 0.f;
#pragma unroll
        for (int c = 0; c < 8; ++c) a += s_red[tid + ND*c];
        s_q[tid] = a;
    }
    __syncthreads();

    // softmax shift-invariance: curr@Wk_top term cancels. Bounded scores ->
    // no max subtraction. Base-2 scores: p = exp2(sd), one v_exp_f32.
    // Only compacted (valid) rows are ever loaded.

    // ---- qk[e] = NORM*log2e * sum_d q[d] * Wk_bot[e,d]  (32 slots x 4 rows) ----
    {
        const float4 q4 = *reinterpret_cast<const float4*>(&s_q[la*4]);
#pragma unroll
        for (int j = 0; j < 4; ++j) {
            const int e = stream*4 + j;
            const float4 wr = *reinterpret_cast<const float4*>(&w_k[(ND + e)*ND + la*4]);
            float p = q4.x*wr.x + q4.y*wr.y + q4.z*wr.z + q4.w*wr.w;
            p = red32(p);
            if (la == 0) s_qk[e] = NORM_LOG2E * p;
        }
    }
    __syncthreads();

    // ---- main loop: perfectly balanced over compacted list ----
    const float4 qk4 = *reinterpret_cast<const float4*>(&s_qk[la*4]);
    float l_run = 0.f;
    float4 acc = make_float4(0.f, 0.f, 0.f, 0.f);

    int i = stream;
    for (; i + NSTREAM < C; i += 2*NSTREAM) {
        const int n0 = s_idx[i];
        const int n1 = s_idx[i + NSTREAM];
        const vf4 x0 = *reinterpret_cast<const vf4*>(&nb_row[(size_t)n0 * ND + la*4]);
        const vf4 x1 = *reinterpret_cast<const vf4*>(&nb_row[(size_t)n1 * ND + la*4]);
        float sd0 = x0.x*qk4.x + x0.y*qk4.y + x0.z*qk4.z + x0.w*qk4.w;
        float sd1 = x1.x*qk4.x + x1.y*qk4.y + x1.z*qk4.z + x1.w*qk4.w;
        sd0 = red32(sd0);
        sd1 = red32(sd1);
        const float p0 = exp2f(sd0);
        const float p1 = exp2f(sd1);
        l_run += p0 + p1;
        acc.x += fmaf(p1, x1.x, p0*x0.x);
        acc.y += fmaf(p1, x1.y, p0*x0.y);
        acc.z += fmaf(p1, x1.z, p0*x0.z);
        acc.w += fmaf(p1, x1.w, p0*x0.w);
    }
    if (i < C) {
        const int n = s_idx[i];
        const vf4 x = *reinterpret_cast<const vf4*>(&nb_row[(size_t)n * ND + la*4]);
        float sd = x.x*qk4.x + x.y*qk4.y + x.z*qk4.z + x.w*qk4.w;
        sd = red32(sd);
        const float p = exp2f(sd);
        l_run += p;
        acc.x = fmaf(p, x.x, acc.x);
        acc.y = fmaf(p, x.y, acc.y);
        acc.z = fmaf(p, x.z, acc.z);
        acc.w = fmaf(p, x.w, acc.w);
    }

    // ---- combine 32 slots (plain sums) ----
    if (la == 0) s_l[stream] = l_run;
    *reinterpret_cast<float4*>(&s_acc[stream][la*4]) = acc;
    __syncthreads();
    {
        float hv = 0.f;
#pragma unroll
        for (int i2 = ch*4; i2 < ch*4 + 4; ++i2) hv += s_acc[i2][d];
        s_red[tid] = hv;
    }
    __syncthreads();
    if (tid < ND) {
        float hv = 0.f;
#pragma unroll
        for (int c = 0; c < 8; ++c) hv += s_red[d + ND*c];
        float lg = 0.f;
#pragma unroll
        for (int i2 = 0; i2 < NSTREAM; ++i2) lg += s_l[i2];
        s_qk[d] = hv / lg;   // hn = attn-weighted node emb
    }
    __syncthreads();

    // ---- h[d] = curr@Wv_top + hn@Wv_bot  (256 rows over 8 chunks of 32) ----
    {
        const float* src = (ch < 4) ? s_inq : (s_qk - ND);  // e<128: curr, else hn
        float a = 0.f;
#pragma unroll 4
        for (int e = ch*32; e < ch*32 + 32; ++e)
            a = fmaf(src[e], w_v[e*ND + d], a);
        s_red[tid] = a;
    }
    __syncthreads();
    if (tid < ND) {
        float a = 0.f;
#pragma unroll
        for (int c = 0; c < 8; ++c) a += s_red[tid + ND*c];
        s_h[tid] = a;
    }
    __syncthreads();

    // ---- out[d] = dot(h, w_out[d,:]) + b_out[d] + q[d]  (32 slots x 4 rows) ----
    {
        const float4 h4 = *reinterpret_cast<const float4*>(&s_h[la*4]);
#pragma unroll
        for (int j = 0; j < 4; ++j) {
            const int dd = stream*4 + j;
            const float4 wr = *reinterpret_cast<const float4*>(&w_out[dd*ND + la*4]);
            float p = h4.x*wr.x + h4.y*wr.y + h4.z*wr.z + h4.w*wr.w;
            p = red32(p);
            if (la == 0) out[(size_t)b*ND + dd] = p + b_out[dd] + s_q[dd];
        }
    }
}

extern "C" void kernel_launch(void* const* d_in, const int* in_sizes, int n_in,
                              void* d_out, int out_size, void* d_ws, size_t ws_size,
                              hipStream_t stream) {
    const float* node_emb = (const float*)d_in[0];
    const float* state    = (const float*)d_in[1];
    const int*   curr_id  = (const int*)d_in[2];
    const int*   next_id  = (const int*)d_in[3];
    const int*   mask     = (const int*)d_in[4];
    const float* w_q     = (const float*)d_in[5];
    const float* w_k     = (const float*)d_in[6];
    const float* w_v     = (const float*)d_in[7];
    const float* w_state = (const float*)d_in[8];
    const float* b_state = (const float*)d_in[9];
    const float* w_out   = (const float*)d_in[10];
    const float* b_out   = (const float*)d_in[11];
    float* outp = (float*)d_out;

    hipLaunchKernelGGL(attn_edge_kernel, dim3(NB), dim3(THREADS), 0, stream,
                       node_emb, state, curr_id, next_id, mask,
                       w_q, w_k, w_v, w_state, b_state, w_out, b_out, outp);
}

// Round 13
// 36.480 us; speedup vs baseline: 1.0309x; 1.0309x over previous
//
#include <hip/hip_runtime.h>

#define NB 512
#define NN 1000
#define ND 128
#define NS 8
#define THREADS 1024
#define NSTREAM 32
#define NWAVE 16

static constexpr float NORM_LOG2E = 0.12752455581290256f; // (1/sqrt(128)) * log2(e)

typedef float vf4 __attribute__((ext_vector_type(4)));

// 32-lane all-lanes sum: 4 DPP (VALU) + 1 ds_swizzle(xor16).
__device__ __forceinline__ float red32(float v) {
    int x;
    x = __float_as_int(v);
    v += __int_as_float(__builtin_amdgcn_update_dpp(0, x, 0xB1, 0xF, 0xF, true));  // quad_perm xor1
    x = __float_as_int(v);
    v += __int_as_float(__builtin_amdgcn_update_dpp(0, x, 0x4E, 0xF, 0xF, true));  // quad_perm xor2
    x = __float_as_int(v);
    v += __int_as_float(__builtin_amdgcn_update_dpp(0, x, 0x124, 0xF, 0xF, true)); // row_ror:4
    x = __float_as_int(v);
    v += __int_as_float(__builtin_amdgcn_update_dpp(0, x, 0x128, 0xF, 0xF, true)); // row_ror:8
    x = __float_as_int(v);
    v += __int_as_float(__builtin_amdgcn_ds_swizzle(x, 0x401F));                   // xor16
    return v;
}

__global__ __launch_bounds__(THREADS, 8)
void attn_edge_kernel(const float* __restrict__ node_emb,
                      const float* __restrict__ state,
                      const int* __restrict__ curr_id,
                      const int* __restrict__ next_id,
                      const int* __restrict__ mask,
                      const float* __restrict__ w_q,
                      const float* __restrict__ w_k,
                      const float* __restrict__ w_v,
                      const float* __restrict__ w_state,
                      const float* __restrict__ b_state,
                      const float* __restrict__ w_out,
                      const float* __restrict__ b_out,
                      float* __restrict__ out)
{
    const int b = blockIdx.x;
    const int tid = threadIdx.x;
    const int lane = tid & 63;
    const int wv = tid >> 6;          // wave 0..15
    const int half = lane >> 5;       // half-wave 0/1
    const int la = lane & 31;         // lane in half
    const int stream = wv * 2 + half; // 32 (wv,half) slots

    __shared__ __align__(16) float s_inq[3*ND];   // [curr | next | state_emb]
    __shared__ __align__(16) float s_q[ND];
    __shared__ __align__(16) float s_qk[ND];      // later reused for hn
    __shared__ __align__(16) float s_red[THREADS];
    __shared__ __align__(16) float s_acc[NSTREAM][ND];
    __shared__ __align__(16) float s_h[ND];
    __shared__ float s_l[NSTREAM];                // per-slot exp-sums
    __shared__ unsigned short s_idx[1024];        // compacted valid-node list
    __shared__ int s_cnt[NWAVE];

    const float* nb_row = node_emb + (size_t)b * NN * ND;
    const int* mrow = mask + (size_t)b * NN;

    // ---- compact valid nodes: wave w covers [w*64, w*64+64) ----
    {
        const int n = wv * 64 + lane;
        const int mv = (n < NN) ? mrow[n] : 0;
        const unsigned long long bal = __ballot(mv != 0);
        if (lane == 0) s_cnt[wv] = __popcll(bal);
        __syncthreads();
        int base = 0;
#pragma unroll
        for (int w = 0; w < NWAVE; ++w) base += (w < wv) ? s_cnt[w] : 0;
        if (mv) {
            const int pos = base + __popcll(bal & ((1ULL << lane) - 1ULL));
            s_idx[pos] = (unsigned short)n;
        }
    }

    // ---- input_q = [curr_emb, next_emb, state_emb] ----
    if (tid < ND) {
        const int cid = curr_id[b];
        const int nid = next_id[b];
        s_inq[tid]      = nb_row[(size_t)cid * ND + tid];
        s_inq[ND + tid] = nb_row[(size_t)nid * ND + tid];
        float se = b_state[tid];
#pragma unroll
        for (int s = 0; s < NS; ++s)
            se = fmaf(state[b*NS + s], w_state[tid*NS + s], se);
        s_inq[2*ND + tid] = se;
    }
    __syncthreads();

    int C = 0;  // total valid count (wave-uniform)
#pragma unroll
    for (int w = 0; w < NWAVE; ++w) C += s_cnt[w];

    const int d  = tid & (ND-1);
    const int ch = tid >> 7;          // chunk 0..7

    // ---- q[d] = sum_e inq[e] * w_q[e,d]  (384 rows over 8 chunks of 48) ----
    {
        float a = 0.f;
#pragma unroll 4
        for (int e = ch*48; e < ch*48 + 48; ++e)
            a = fmaf(s_inq[e], w_q[e*ND + d], a);
        s_red[tid] = a;
    }
    __syncthreads();
    if (tid < ND) {
        float a = 0.f;
#pragma unroll
        for (int c = 0; c < 8; ++c) a += s_red[tid + ND*c];
        s_q[tid] = a;
    }
    __syncthreads();

    // softmax shift-invariance: curr@Wk_top term cancels. Bounded scores ->
    // no max subtraction. Base-2 scores: p = exp2(sd), one v_exp_f32.
    // Only compacted (valid) rows are ever loaded.

    // ---- qk[e] = NORM*log2e * sum_d q[d] * Wk_bot[e,d]  (32 slots x 4 rows) ----
    {
        const float4 q4 = *reinterpret_cast<const float4*>(&s_q[la*4]);
#pragma unroll
        for (int j = 0; j < 4; ++j) {
            const int e = stream*4 + j;
            const float4 wr = *reinterpret_cast<const float4*>(&w_k[(ND + e)*ND + la*4]);
            float p = q4.x*wr.x + q4.y*wr.y + q4.z*wr.z + q4.w*wr.w;
            p = red32(p);
            if (la == 0) s_qk[e] = NORM_LOG2E * p;
        }
    }
    __syncthreads();

    // ---- main loop: 4-deep pipeline over compacted list ----
    const float4 qk4 = *reinterpret_cast<const float4*>(&s_qk[la*4]);
    float l_run = 0.f;
    float4 acc = make_float4(0.f, 0.f, 0.f, 0.f);

    int i = stream;
    for (; i + 3*NSTREAM < C; i += 4*NSTREAM) {
        const int n0 = s_idx[i];
        const int n1 = s_idx[i + NSTREAM];
        const int n2 = s_idx[i + 2*NSTREAM];
        const int n3 = s_idx[i + 3*NSTREAM];
        const vf4 x0 = *reinterpret_cast<const vf4*>(&nb_row[(size_t)n0 * ND + la*4]);
        const vf4 x1 = *reinterpret_cast<const vf4*>(&nb_row[(size_t)n1 * ND + la*4]);
        const vf4 x2 = *reinterpret_cast<const vf4*>(&nb_row[(size_t)n2 * ND + la*4]);
        const vf4 x3 = *reinterpret_cast<const vf4*>(&nb_row[(size_t)n3 * ND + la*4]);
        float sd0 = x0.x*qk4.x + x0.y*qk4.y + x0.z*qk4.z + x0.w*qk4.w;
        float sd1 = x1.x*qk4.x + x1.y*qk4.y + x1.z*qk4.z + x1.w*qk4.w;
        float sd2 = x2.x*qk4.x + x2.y*qk4.y + x2.z*qk4.z + x2.w*qk4.w;
        float sd3 = x3.x*qk4.x + x3.y*qk4.y + x3.z*qk4.z + x3.w*qk4.w;
        sd0 = red32(sd0);
        sd1 = red32(sd1);
        sd2 = red32(sd2);
        sd3 = red32(sd3);
        const float p0 = exp2f(sd0);
        const float p1 = exp2f(sd1);
        const float p2 = exp2f(sd2);
        const float p3 = exp2f(sd3);
        l_run += (p0 + p1) + (p2 + p3);
        acc.x += fmaf(p1, x1.x, p0*x0.x) + fmaf(p3, x3.x, p2*x2.x);
        acc.y += fmaf(p1, x1.y, p0*x0.y) + fmaf(p3, x3.y, p2*x2.y);
        acc.z += fmaf(p1, x1.z, p0*x0.z) + fmaf(p3, x3.z, p2*x2.z);
        acc.w += fmaf(p1, x1.w, p0*x0.w) + fmaf(p3, x3.w, p2*x2.w);
    }
    for (; i < C; i += NSTREAM) {
        const int n = s_idx[i];
        const vf4 x = *reinterpret_cast<const vf4*>(&nb_row[(size_t)n * ND + la*4]);
        float sd = x.x*qk4.x + x.y*qk4.y + x.z*qk4.z + x.w*qk4.w;
        sd = red32(sd);
        const float p = exp2f(sd);
        l_run += p;
        acc.x = fmaf(p, x.x, acc.x);
        acc.y = fmaf(p, x.y, acc.y);
        acc.z = fmaf(p, x.z, acc.z);
        acc.w = fmaf(p, x.w, acc.w);
    }

    // ---- combine 32 slots (plain sums) ----
    if (la == 0) s_l[stream] = l_run;
    *reinterpret_cast<float4*>(&s_acc[stream][la*4]) = acc;
    __syncthreads();
    {
        float hv = 0.f;
#pragma unroll
        for (int i2 = ch*4; i2 < ch*4 + 4; ++i2) hv += s_acc[i2][d];
        s_red[tid] = hv;
    }
    __syncthreads();
    if (tid < ND) {
        float hv = 0.f;
#pragma unroll
        for (int c = 0; c < 8; ++c) hv += s_red[d + ND*c];
        float lg = 0.f;
#pragma unroll
        for (int i2 = 0; i2 < NSTREAM; ++i2) lg += s_l[i2];
        s_qk[d] = hv / lg;   // hn = attn-weighted node emb
    }
    __syncthreads();

    // ---- h[d] = curr@Wv_top + hn@Wv_bot  (256 rows over 8 chunks of 32) ----
    {
        const float* src = (ch < 4) ? s_inq : (s_qk - ND);  // e<128: curr, else hn
        float a = 0.f;
#pragma unroll 4
        for (int e = ch*32; e < ch*32 + 32; ++e)
            a = fmaf(src[e], w_v[e*ND + d], a);
        s_red[tid] = a;
    }
    __syncthreads();
    if (tid < ND) {
        float a = 0.f;
#pragma unroll
        for (int c = 0; c < 8; ++c) a += s_red[tid + ND*c];
        s_h[tid] = a;
    }
    __syncthreads();

    // ---- out[d] = dot(h, w_out[d,:]) + b_out[d] + q[d]  (32 slots x 4 rows) ----
    {
        const float4 h4 = *reinterpret_cast<const float4*>(&s_h[la*4]);
#pragma unroll
        for (int j = 0; j < 4; ++j) {
            const int dd = stream*4 + j;
            const float4 wr = *reinterpret_cast<const float4*>(&w_out[dd*ND + la*4]);
            float p = h4.x*wr.x + h4.y*wr.y + h4.z*wr.z + h4.w*wr.w;
            p = red32(p);
            if (la == 0) out[(size_t)b*ND + dd] = p + b_out[dd] + s_q[dd];
        }
    }
}

extern "C" void kernel_launch(void* const* d_in, const int* in_sizes, int n_in,
                              void* d_out, int out_size, void* d_ws, size_t ws_size,
                              hipStream_t stream) {
    const float* node_emb = (const float*)d_in[0];
    const float* state    = (const float*)d_in[1];
    const int*   curr_id  = (const int*)d_in[2];
    const int*   next_id  = (const int*)d_in[3];
    const int*   mask     = (const int*)d_in[4];
    const float* w_q     = (const float*)d_in[5];
    const float* w_k     = (const float*)d_in[6];
    const float* w_v     = (const float*)d_in[7];
    const float* w_state = (const float*)d_in[8];
    const float* b_state = (const float*)d_in[9];
    const float* w_out   = (const float*)d_in[10];
    const float* b_out   = (const float*)d_in[11];
    float* outp = (float*)d_out;

    hipLaunchKernelGGL(attn_edge_kernel, dim3(NB), dim3(THREADS), 0, stream,
                       node_emb, state, curr_id, next_id, mask,
                       w_q, w_k, w_v, w_state, b_state, w_out, b_out, outp);
}